// Round 1
// baseline (2897.316 us; speedup 1.0000x reference)
//
#include <hip/hip_runtime.h>

#define NN 100000
#define NE 600000
#define D  128

// ---------------------------------------------------------------- count deg
__global__ void count_deg(const int* __restrict__ dst, int* __restrict__ cnt, int E) {
    int e = blockIdx.x * blockDim.x + threadIdx.x;
    if (e < E) {
        int d = dst[e];
        if ((unsigned)d < (unsigned)NN) atomicAdd(&cnt[d], 1);
    }
}

// ---------------------------------------------------------------- g = (x @ W^T) * dinv[row]
// Block: 256 threads = 4 waves. Wave (wid&1) covers cols 0-63 / 64-127;
// wave pair (wid>>1) covers rows rgrp..rgrp+7 of a 16-row tile.
// Each lane holds its W row (128 floats) in 32 float4 registers.
__global__ __launch_bounds__(256) void gemm_scale(
        const float* __restrict__ x, const float* __restrict__ W,
        const int* __restrict__ cnt, float* __restrict__ g, int n) {
    __shared__ float xs[16][D];                    // 8 KiB
    const int tid  = threadIdx.x;
    const int wid  = tid >> 6;
    const int lane = tid & 63;
    const int col  = (wid & 1) * 64 + lane;        // 0..127
    const int rgrp = (wid >> 1) * 8;               // 0 or 8

    float4 w[32];
    const float4* W4 = (const float4*)(W + (size_t)col * D);
    #pragma unroll
    for (int t = 0; t < 32; ++t) w[t] = W4[t];

    for (int row0 = blockIdx.x * 16; row0 < n; row0 += gridDim.x * 16) {
        __syncthreads();   // previous tile's readers done before overwrite
        {
            const int nrows = min(16, n - row0);
            #pragma unroll
            for (int t = 0; t < 2; ++t) {
                int i4 = tid + t * 256;            // 0..511 float4 slots
                int r  = i4 >> 5;                  // 32 float4 per row
                int c  = i4 & 31;
                if (r < nrows)
                    ((float4*)xs[r])[c] =
                        ((const float4*)(x + (size_t)(row0 + r) * D))[c];
            }
        }
        __syncthreads();

        const int nr = min(8, n - row0 - rgrp);
        if (nr > 0) {
            float acc[8];
            #pragma unroll
            for (int r = 0; r < 8; ++r) acc[r] = 0.f;
            #pragma unroll
            for (int t = 0; t < 32; ++t) {
                #pragma unroll
                for (int r = 0; r < 8; ++r) {
                    float4 xv = ((const float4*)xs[rgrp + r])[t];   // wave-uniform broadcast
                    acc[r] = fmaf(xv.x, w[t].x, acc[r]);
                    acc[r] = fmaf(xv.y, w[t].y, acc[r]);
                    acc[r] = fmaf(xv.z, w[t].z, acc[r]);
                    acc[r] = fmaf(xv.w, w[t].w, acc[r]);
                }
            }
            #pragma unroll
            for (int r = 0; r < 8; ++r) {
                int row = row0 + rgrp + r;
                if (row < n) {
                    float dinv = rsqrtf((float)(cnt[row] + 1));
                    g[(size_t)row * D + col] = acc[r] * dinv;
                }
            }
        }
    }
}

// ---------------------------------------------------------------- scatter: out[dst] += g[src]
// 32 lanes per edge, float4 per lane -> 4 f32 atomics.
__global__ void scatter_edges(const int* __restrict__ src, const int* __restrict__ dst,
                              const float* __restrict__ g, float* __restrict__ out, int E) {
    int idx = blockIdx.x * blockDim.x + threadIdx.x;
    int e = idx >> 5;
    if (e >= E) return;
    int f = (idx & 31) * 4;
    int s = src[e];
    int d = dst[e];
    if ((unsigned)s >= (unsigned)NN || (unsigned)d >= (unsigned)NN) return;
    const float4 v = *(const float4*)(g + (size_t)s * D + f);
    float* o = out + (size_t)d * D + f;
    atomicAdd(o + 0, v.x);
    atomicAdd(o + 1, v.y);
    atomicAdd(o + 2, v.z);
    atomicAdd(o + 3, v.w);
}

// ---------------------------------------------------------------- out = x + relu(dinv*(agg+g) + b)
__global__ void finalize(const float* __restrict__ x, const float* __restrict__ g,
                         const int* __restrict__ cnt, const float* __restrict__ bias,
                         float* __restrict__ out, int n) {
    size_t idx = (size_t)blockIdx.x * blockDim.x + threadIdx.x;
    size_t total = (size_t)n * (D / 4);
    if (idx >= total) return;
    int row = (int)(idx >> 5);
    int c4  = (int)(idx & 31);
    float dinv = rsqrtf((float)(cnt[row] + 1));
    float4 a  = ((const float4*)out)[idx];
    float4 gg = ((const float4*)g)[idx];
    float4 xv = ((const float4*)x)[idx];
    float4 b  = ((const float4*)bias)[c4];
    float4 r;
    r.x = xv.x + fmaxf(fmaf(dinv, a.x + gg.x, b.x), 0.f);
    r.y = xv.y + fmaxf(fmaf(dinv, a.y + gg.y, b.y), 0.f);
    r.z = xv.z + fmaxf(fmaf(dinv, a.z + gg.z, b.z), 0.f);
    r.w = xv.w + fmaxf(fmaf(dinv, a.w + gg.w, b.w), 0.f);
    ((float4*)out)[idx] = r;
}

// ---------------------------------------------------------------- launch
extern "C" void kernel_launch(void* const* d_in, const int* in_sizes, int n_in,
                              void* d_out, int out_size, void* d_ws, size_t ws_size,
                              hipStream_t stream) {
    const float* x    = (const float*)d_in[0];
    const int*   ei   = (const int*)d_in[1];      // [2][NE], int32
    const float* W    = (const float*)d_in[2];    // [D][D]
    const float* bias = (const float*)d_in[3];    // [D]
    float* out = (float*)d_out;

    const int n = NN, E = NE;
    int*   cnt = (int*)d_ws;
    size_t goff = ((size_t)n * sizeof(int) + 255) & ~(size_t)255;
    float* g   = (float*)((char*)d_ws + goff);

    const int* src = ei;
    const int* dst = ei + E;

    hipMemsetAsync(cnt, 0, (size_t)n * sizeof(int), stream);
    hipMemsetAsync(out, 0, (size_t)out_size * sizeof(float), stream);

    count_deg<<<(E + 255) / 256, 256, 0, stream>>>(dst, cnt, E);
    gemm_scale<<<768, 256, 0, stream>>>(x, W, cnt, g, n);
    scatter_edges<<<(E * 32 + 255) / 256, 256, 0, stream>>>(src, dst, g, out, E);
    finalize<<<(int)(((size_t)n * (D / 4) + 255) / 256), 256, 0, stream>>>(
        x, g, cnt, bias, out, n);
}

// Round 2
// 172.823 us; speedup vs baseline: 16.7647x; 16.7647x over previous
//
#include <hip/hip_runtime.h>

#define NN 100000
#define NE 600000
#define D  128
#define NB ((NN + 255) / 256)   // 391 blocks for node-sized arrays

typedef __bf16 bf16x8 __attribute__((ext_vector_type(8)));
typedef float  f32x4  __attribute__((ext_vector_type(4)));

__device__ inline float bf2f(unsigned short u) {
    unsigned int v = ((unsigned int)u) << 16;
    float f;
    __builtin_memcpy(&f, &v, 4);
    return f;
}

// ---------------------------------------------------------------- in-degree histogram
__global__ void count_deg(const int* __restrict__ dst, int* __restrict__ cnt, int E) {
    int e = blockIdx.x * blockDim.x + threadIdx.x;
    if (e < E) {
        int d = dst[e];
        if ((unsigned)d < (unsigned)NN) atomicAdd(&cnt[d], 1);
    }
}

// ---------------------------------------------------------------- per-block sums for scan
__global__ void k_bsum(const int* __restrict__ cnt, int* __restrict__ bsum) {
    int i = blockIdx.x * 256 + threadIdx.x;
    int v = (i < NN) ? cnt[i] : 0;
    #pragma unroll
    for (int o = 32; o; o >>= 1) v += __shfl_down(v, o);
    __shared__ int ws[4];
    if ((threadIdx.x & 63) == 0) ws[threadIdx.x >> 6] = v;
    __syncthreads();
    if (threadIdx.x == 0) bsum[blockIdx.x] = ws[0] + ws[1] + ws[2] + ws[3];
}

// ---------------------------------------------------------------- scan the 391 block sums (1 block)
__global__ void k_scanb(const int* __restrict__ bsum, int* __restrict__ bscan) {
    __shared__ int s[512];
    int t = threadIdx.x;
    s[t] = (t < NB) ? bsum[t] : 0;
    __syncthreads();
    for (int d = 1; d < 512; d <<= 1) {
        int v = (t >= d) ? s[t - d] : 0;
        __syncthreads();
        s[t] += v;
        __syncthreads();
    }
    if (t < NB) bscan[t] = s[t];   // inclusive
}

// ---------------------------------------------------------------- exclusive offsets + dinv
__global__ void k_off(const int* __restrict__ cnt, const int* __restrict__ bscan,
                      int* __restrict__ off, int* __restrict__ cur, float* __restrict__ dinv) {
    __shared__ int s[256];
    int t = threadIdx.x, b = blockIdx.x;
    int i = b * 256 + t;
    int v = (i < NN) ? cnt[i] : 0;
    s[t] = v;
    __syncthreads();
    for (int d = 1; d < 256; d <<= 1) {
        int u = (t >= d) ? s[t - d] : 0;
        __syncthreads();
        s[t] += u;
        __syncthreads();
    }
    if (i < NN) {
        int ex = s[t] - v + (b ? bscan[b - 1] : 0);
        off[i] = ex;
        cur[i] = ex;
        dinv[i] = rsqrtf((float)(v + 1));   // deg includes self loop
    }
}

// ---------------------------------------------------------------- CSR fill (src list per dst)
__global__ void k_fill(const int* __restrict__ src, const int* __restrict__ dst,
                       int* __restrict__ cur, int* __restrict__ adj, int E) {
    int e = blockIdx.x * blockDim.x + threadIdx.x;
    if (e >= E) return;
    int d = dst[e], s = src[e];
    if ((unsigned)d >= (unsigned)NN || (unsigned)s >= (unsigned)NN) return;
    adj[atomicAdd(&cur[d], 1)] = s;
}

// ---------------------------------------------------------------- pack W into MFMA B-frag layout (bf16)
// slot(kt,ct,lane) holds B[k0..k0+7][col] = W[col][k0..k0+7],
// col = ct*16+(lane&15), k0 = kt*32+((lane>>4)&3)*8
__global__ void k_wprep(const float* __restrict__ W, __bf16* __restrict__ wf) {
    int t = blockIdx.x * 256 + threadIdx.x;   // 0..2047
    int lane = t & 63, ct = (t >> 6) & 7, kt = t >> 9;
    int col = ct * 16 + (lane & 15);
    int k0  = kt * 32 + ((lane >> 4) & 3) * 8;
    const float* wp = W + (size_t)col * D + k0;
    __bf16* o = wf + (size_t)t * 8;
    #pragma unroll
    for (int j = 0; j < 8; ++j) o[j] = (__bf16)wp[j];
}

// ---------------------------------------------------------------- g = (x @ W^T) * dinv[row], bf16
// One wave per 16-row tile; 8 col-tiles x 4 k-tiles = 32 MFMA.
__global__ __launch_bounds__(256) void k_gemm(const float* __restrict__ x,
                                              const __bf16* __restrict__ wf,
                                              const float* __restrict__ dinv,
                                              __bf16* __restrict__ g) {
    int gid = blockIdx.x * 4 + (threadIdx.x >> 6);
    if (gid >= NN / 16) return;                     // 100000/16 = 6250 exact
    int lane = threadIdx.x & 63;
    int row0 = gid * 16;
    int rA   = row0 + (lane & 15);
    int kg   = lane >> 4;                           // 0..3

    f32x4 acc[8];
    #pragma unroll
    for (int ct = 0; ct < 8; ++ct) acc[ct] = (f32x4){0.f, 0.f, 0.f, 0.f};

    #pragma unroll
    for (int kt = 0; kt < 4; ++kt) {
        const float4* xp = (const float4*)(x + (size_t)rA * D + kt * 32 + kg * 8);
        float4 x0 = xp[0];
        float4 x1 = xp[1];
        bf16x8 a;
        a[0] = (__bf16)x0.x; a[1] = (__bf16)x0.y; a[2] = (__bf16)x0.z; a[3] = (__bf16)x0.w;
        a[4] = (__bf16)x1.x; a[5] = (__bf16)x1.y; a[6] = (__bf16)x1.z; a[7] = (__bf16)x1.w;
        const bf16x8* wfp = (const bf16x8*)wf + (size_t)kt * 512 + lane;
        #pragma unroll
        for (int ct = 0; ct < 8; ++ct) {
            bf16x8 b = wfp[ct * 64];
            acc[ct] = __builtin_amdgcn_mfma_f32_16x16x32_bf16(a, b, acc[ct], 0, 0, 0);
        }
    }

    // C/D layout: col = lane&15, row = (lane>>4)*4 + reg
    int colb = lane & 15;
    int rre  = row0 + kg * 4;
    float dv[4];
    #pragma unroll
    for (int i = 0; i < 4; ++i) dv[i] = dinv[rre + i];
    #pragma unroll
    for (int ct = 0; ct < 8; ++ct) {
        #pragma unroll
        for (int i = 0; i < 4; ++i)
            g[(size_t)(rre + i) * D + ct * 16 + colb] = (__bf16)(acc[ct][i] * dv[i]);
    }
}

// ---------------------------------------------------------------- gather-aggregate + fused epilogue
// One wave per node: acc = g[node] + sum g[adj]; out = x + relu(dinv*acc + bias)
__global__ __launch_bounds__(256) void k_agg(const float* __restrict__ x,
                                             const __bf16* __restrict__ g,
                                             const int* __restrict__ off,
                                             const int* __restrict__ cnt,
                                             const float* __restrict__ dinv,
                                             const float* __restrict__ bias,
                                             const int* __restrict__ adj,
                                             float* __restrict__ out) {
    int node = blockIdx.x * 4 + (threadIdx.x >> 6);
    if (node >= NN) return;
    int lane = threadIdx.x & 63;
    int c0 = lane * 2;

    unsigned int u = *(const unsigned int*)(g + (size_t)node * D + c0);  // self loop
    float a0 = bf2f((unsigned short)u);
    float a1 = bf2f((unsigned short)(u >> 16));

    int beg = off[node];
    int end = beg + cnt[node];
    for (int i = beg; i < end; ++i) {
        int s = adj[i];
        unsigned int v = *(const unsigned int*)(g + (size_t)s * D + c0);
        a0 += bf2f((unsigned short)v);
        a1 += bf2f((unsigned short)(v >> 16));
    }

    float dv = dinv[node];
    float2 bv = *(const float2*)(bias + c0);
    float2 xv = *(const float2*)(x + (size_t)node * D + c0);
    float2 r;
    r.x = xv.x + fmaxf(fmaf(dv, a0, bv.x), 0.f);
    r.y = xv.y + fmaxf(fmaf(dv, a1, bv.y), 0.f);
    *(float2*)(out + (size_t)node * D + c0) = r;
}

// ---------------------------------------------------------------- launch
extern "C" void kernel_launch(void* const* d_in, const int* in_sizes, int n_in,
                              void* d_out, int out_size, void* d_ws, size_t ws_size,
                              hipStream_t stream) {
    const float* x    = (const float*)d_in[0];
    const int*   ei   = (const int*)d_in[1];      // [2][NE], int32 (verified round 1)
    const float* W    = (const float*)d_in[2];    // [D][D]
    const float* bias = (const float*)d_in[3];    // [D]
    float* out = (float*)d_out;

    const int* src = ei;
    const int* dst = ei + NE;

    // workspace layout (all 256-B aligned)
    char* p = (char*)d_ws;
    auto take = [&](size_t bytes) {
        char* q = p;
        p += (bytes + 255) & ~(size_t)255;
        return q;
    };
    int*    cnt   = (int*)take((size_t)NN * 4);
    int*    off   = (int*)take((size_t)NN * 4);
    int*    cur   = (int*)take((size_t)NN * 4);
    int*    bsum  = (int*)take(512 * 4);
    int*    bscan = (int*)take(512 * 4);
    float*  dinv  = (float*)take((size_t)NN * 4);
    int*    adj   = (int*)take((size_t)NE * 4);
    __bf16* wf    = (__bf16*)take((size_t)2048 * 8 * 2);
    __bf16* g     = (__bf16*)take((size_t)NN * D * 2);

    hipMemsetAsync(cnt, 0, (size_t)NN * 4, stream);

    count_deg<<<(NE + 255) / 256, 256, 0, stream>>>(dst, cnt, NE);
    k_bsum  <<<NB, 256, 0, stream>>>(cnt, bsum);
    k_scanb <<<1, 512, 0, stream>>>(bsum, bscan);
    k_off   <<<NB, 256, 0, stream>>>(cnt, bscan, off, cur, dinv);
    k_fill  <<<(NE + 255) / 256, 256, 0, stream>>>(src, dst, cur, adj, NE);
    k_wprep <<<8, 256, 0, stream>>>(W, wf);
    k_gemm  <<<(NN / 16 + 3) / 4, 256, 0, stream>>>(x, wf, dinv, g);
    k_agg   <<<NN / 4, 256, 0, stream>>>(x, g, off, cnt, dinv, bias, adj, out);
}

// Round 3
// 154.628 us; speedup vs baseline: 18.7374x; 1.1177x over previous
//
#include <hip/hip_runtime.h>

#define NN 100000
#define NE 600000
#define D  128

typedef __bf16 bf16x8 __attribute__((ext_vector_type(8)));
typedef __bf16 bf16x4 __attribute__((ext_vector_type(4)));
typedef float  f32x4  __attribute__((ext_vector_type(4)));

__device__ inline float bf2f(unsigned short u) {
    unsigned int v = ((unsigned int)u) << 16;
    float f;
    __builtin_memcpy(&f, &v, 4);
    return f;
}

// ---------------------------------------------------------------- in-degree histogram
__global__ void count_deg(const int* __restrict__ dst, int* __restrict__ cnt, int E) {
    int e = blockIdx.x * blockDim.x + threadIdx.x;
    if (e < E) {
        int d = dst[e];
        if ((unsigned)d < (unsigned)NN) atomicAdd(&cnt[d], 1);
    }
}

// ---------------------------------------------------------------- offsets via block scan + atomic base
// CSR bucket ordering is irrelevant (sum commutes), so block bases come from
// one global atomicAdd instead of an ordered cross-block scan.
__global__ __launch_bounds__(256) void k_off2(const int* __restrict__ cnt,
                                              int* __restrict__ gctr,
                                              int* __restrict__ off, int* __restrict__ cur,
                                              float* __restrict__ dinv) {
    __shared__ int s[256];
    __shared__ int base;
    int t = threadIdx.x, b = blockIdx.x;
    int i = b * 256 + t;
    int v = (i < NN) ? cnt[i] : 0;
    s[t] = v;
    __syncthreads();
    for (int d = 1; d < 256; d <<= 1) {
        int u = (t >= d) ? s[t - d] : 0;
        __syncthreads();
        s[t] += u;
        __syncthreads();
    }
    if (t == 255) base = atomicAdd(gctr, s[255]);
    __syncthreads();
    if (i < NN) {
        int ex = base + s[t] - v;
        off[i] = ex;
        cur[i] = ex;
        dinv[i] = rsqrtf((float)(v + 1));   // deg includes self loop
    }
}

// ---------------------------------------------------------------- CSR fill (src list per dst)
__global__ void k_fill(const int* __restrict__ src, const int* __restrict__ dst,
                       int* __restrict__ cur, int* __restrict__ adj, int E) {
    int e = blockIdx.x * blockDim.x + threadIdx.x;
    if (e >= E) return;
    int d = dst[e], s = src[e];
    if ((unsigned)d >= (unsigned)NN || (unsigned)s >= (unsigned)NN) return;
    adj[atomicAdd(&cur[d], 1)] = s;
}

// ---------------------------------------------------------------- pack W into MFMA frag layout + zero dummy row
// slot(kt,ct,lane) holds W[col][k0..k0+7], col = ct*16+(lane&15), k0 = kt*32+((lane>>4)&3)*8
__global__ void k_wprep(const float* __restrict__ W, __bf16* __restrict__ wf,
                        __bf16* __restrict__ g) {
    int t = blockIdx.x * 256 + threadIdx.x;   // 0..2047
    if (t < D) g[(size_t)NN * D + t] = (__bf16)0.f;   // zero row for branchless agg padding
    int lane = t & 63, ct = (t >> 6) & 7, kt = t >> 9;
    int col = ct * 16 + (lane & 15);
    int k0  = kt * 32 + ((lane >> 4) & 3) * 8;
    const float* wp = W + (size_t)col * D + k0;
    __bf16* o = wf + (size_t)t * 8;
    #pragma unroll
    for (int j = 0; j < 8; ++j) o[j] = (__bf16)wp[j];
}

// ---------------------------------------------------------------- g = (x @ W^T) * dinv[row], bf16
// Computes C = W · x^T so the output fragment is feature-major per lane:
// col(lane&15)=node, row(kg*4+reg)=feature -> 4 consecutive bf16 features -> b64 stores.
__global__ __launch_bounds__(256) void k_gemm(const float* __restrict__ x,
                                              const __bf16* __restrict__ wf,
                                              const float* __restrict__ dinv,
                                              __bf16* __restrict__ g) {
    int gid = blockIdx.x * 4 + (threadIdx.x >> 6);
    if (gid >= NN / 16) return;                     // 100000/16 = 6250 exact
    int lane = threadIdx.x & 63;
    int row0 = gid * 16;
    int node = row0 + (lane & 15);
    int kg   = lane >> 4;                           // 0..3

    f32x4 acc[8];
    #pragma unroll
    for (int ct = 0; ct < 8; ++ct) acc[ct] = (f32x4){0.f, 0.f, 0.f, 0.f};

    #pragma unroll
    for (int kt = 0; kt < 4; ++kt) {
        const float4* xp = (const float4*)(x + (size_t)node * D + kt * 32 + kg * 8);
        float4 x0 = xp[0];
        float4 x1 = xp[1];
        bf16x8 a;                                   // B operand: x^T fragment
        a[0] = (__bf16)x0.x; a[1] = (__bf16)x0.y; a[2] = (__bf16)x0.z; a[3] = (__bf16)x0.w;
        a[4] = (__bf16)x1.x; a[5] = (__bf16)x1.y; a[6] = (__bf16)x1.z; a[7] = (__bf16)x1.w;
        const bf16x8* wfp = (const bf16x8*)wf + (size_t)kt * 512 + lane;
        #pragma unroll
        for (int ct = 0; ct < 8; ++ct) {
            bf16x8 b = wfp[ct * 64];                // A operand: W fragment
            acc[ct] = __builtin_amdgcn_mfma_f32_16x16x32_bf16(b, a, acc[ct], 0, 0, 0);
        }
    }

    float dv = dinv[node];
    #pragma unroll
    for (int ct = 0; ct < 8; ++ct) {
        bf16x4 o;
        #pragma unroll
        for (int i = 0; i < 4; ++i) o[i] = (__bf16)(acc[ct][i] * dv);
        *(bf16x4*)(g + (size_t)node * D + ct * 16 + kg * 4) = o;
    }
}

// ---------------------------------------------------------------- gather-aggregate + fused epilogue
// One wave per node, neighbor loop unrolled 4-deep (padding gathers hit the zero row NN).
__global__ __launch_bounds__(256) void k_agg(const float* __restrict__ x,
                                             const __bf16* __restrict__ g,
                                             const int* __restrict__ off,
                                             const int* __restrict__ cnt,
                                             const float* __restrict__ dinv,
                                             const float* __restrict__ bias,
                                             const int* __restrict__ adj,
                                             float* __restrict__ out) {
    int node = blockIdx.x * 4 + (threadIdx.x >> 6);
    if (node >= NN) return;
    int lane = threadIdx.x & 63;
    int c0 = lane * 2;

    // issue epilogue loads early so their latency overlaps the gather loop
    float2 xv = *(const float2*)(x + (size_t)node * D + c0);
    float2 bv = *(const float2*)(bias + c0);
    float  dv = dinv[node];

    unsigned int u = *(const unsigned int*)(g + (size_t)node * D + c0);  // self loop
    float a0 = bf2f((unsigned short)u);
    float a1 = bf2f((unsigned short)(u >> 16));

    int beg = off[node];
    int end = beg + cnt[node];
    for (int i = beg; i < end; i += 4) {
        int s0 = adj[i];
        int s1 = (i + 1 < end) ? adj[i + 1] : NN;
        int s2 = (i + 2 < end) ? adj[i + 2] : NN;
        int s3 = (i + 3 < end) ? adj[i + 3] : NN;
        unsigned int v0 = *(const unsigned int*)(g + (size_t)s0 * D + c0);
        unsigned int v1 = *(const unsigned int*)(g + (size_t)s1 * D + c0);
        unsigned int v2 = *(const unsigned int*)(g + (size_t)s2 * D + c0);
        unsigned int v3 = *(const unsigned int*)(g + (size_t)s3 * D + c0);
        a0 += bf2f((unsigned short)v0);
        a1 += bf2f((unsigned short)(v0 >> 16));
        a0 += bf2f((unsigned short)v1);
        a1 += bf2f((unsigned short)(v1 >> 16));
        a0 += bf2f((unsigned short)v2);
        a1 += bf2f((unsigned short)(v2 >> 16));
        a0 += bf2f((unsigned short)v3);
        a1 += bf2f((unsigned short)(v3 >> 16));
    }

    float2 r;
    r.x = xv.x + fmaxf(fmaf(dv, a0, bv.x), 0.f);
    r.y = xv.y + fmaxf(fmaf(dv, a1, bv.y), 0.f);
    *(float2*)(out + (size_t)node * D + c0) = r;
}

// ---------------------------------------------------------------- launch
extern "C" void kernel_launch(void* const* d_in, const int* in_sizes, int n_in,
                              void* d_out, int out_size, void* d_ws, size_t ws_size,
                              hipStream_t stream) {
    const float* x    = (const float*)d_in[0];
    const int*   ei   = (const int*)d_in[1];      // [2][NE], int32
    const float* W    = (const float*)d_in[2];    // [D][D]
    const float* bias = (const float*)d_in[3];    // [D]
    float* out = (float*)d_out;

    const int* src = ei;
    const int* dst = ei + NE;

    // workspace layout (all 256-B aligned)
    char* p = (char*)d_ws;
    auto take = [&](size_t bytes) {
        char* q = p;
        p += (bytes + 255) & ~(size_t)255;
        return q;
    };
    int*    cnt  = (int*)take((size_t)NN * 4);
    int*    gctr = (int*)take(256);                      // adjacent to cnt -> one memset
    int*    off  = (int*)take((size_t)NN * 4);
    int*    cur  = (int*)take((size_t)NN * 4);
    float*  dinv = (float*)take((size_t)NN * 4);
    int*    adj  = (int*)take((size_t)(NE + 16) * 4);    // +16 pad for unrolled reads
    __bf16* wf   = (__bf16*)take((size_t)2048 * 8 * 2);
    __bf16* g    = (__bf16*)take((size_t)(NN + 1) * D * 2);  // +1 zero row

    size_t cntPad = (((size_t)NN * 4 + 255) & ~(size_t)255);
    hipMemsetAsync(cnt, 0, cntPad + 256, stream);        // zeroes cnt + gctr

    count_deg<<<(NE + 255) / 256, 256, 0, stream>>>(dst, cnt, NE);
    k_off2 <<<(NN + 255) / 256, 256, 0, stream>>>(cnt, gctr, off, cur, dinv);
    k_fill <<<(NE + 255) / 256, 256, 0, stream>>>(src, dst, cur, adj, NE);
    k_wprep<<<8, 256, 0, stream>>>(W, wf, g);
    k_gemm <<<(NN / 16 + 3) / 4, 256, 0, stream>>>(x, wf, dinv, g);
    k_agg  <<<NN / 4, 256, 0, stream>>>(x, g, off, cnt, dinv, bias, adj, out);
}

// Round 5
// 135.519 us; speedup vs baseline: 21.3795x; 1.1410x over previous
//
#include <hip/hip_runtime.h>

#define NN 100000
#define NE 600000
#define D  128

typedef __bf16 bf16x8 __attribute__((ext_vector_type(8)));
typedef __bf16 bf16x4 __attribute__((ext_vector_type(4)));
typedef float  f32x4  __attribute__((ext_vector_type(4)));

#define GB_CNT  ((NE + 255) / 256)     // 2344 blocks: edge-sized
#define GB_WP   8                      // w-prep blocks
#define GB_GEMM ((NN / 16 + 3) / 4)    // 1563 blocks: gemm tiles

__device__ inline float bflo(unsigned int v) {
    unsigned int t = v << 16; float f; __builtin_memcpy(&f, &t, 4); return f;
}
__device__ inline float bfhi(unsigned int v) {
    unsigned int t = v & 0xffff0000u; float f; __builtin_memcpy(&f, &t, 4); return f;
}

// ------------------------------------------------ A: count_deg ∥ W-prep ∥ zero-row
__global__ __launch_bounds__(256) void k_A(const int* __restrict__ dst, int* __restrict__ cnt,
                                           const float* __restrict__ W, __bf16* __restrict__ wf,
                                           __bf16* __restrict__ g) {
    if (blockIdx.x < GB_CNT) {
        int e = blockIdx.x * 256 + threadIdx.x;
        if (e < NE) {
            int d = dst[e];
            if ((unsigned)d < (unsigned)NN) atomicAdd(&cnt[d], 1);
        }
    } else {
        int t = (blockIdx.x - GB_CNT) * 256 + threadIdx.x;   // 0..2047
        if (t < D) g[(size_t)NN * D + t] = (__bf16)0.f;      // zero row for masked gathers
        int lane = t & 63, ct = (t >> 6) & 7, kt = t >> 9;
        int col = ct * 16 + (lane & 15);
        int k0  = kt * 32 + ((lane >> 4) & 3) * 8;
        const float* wp = W + (size_t)col * D + k0;
        __bf16* o = wf + (size_t)t * 8;
        #pragma unroll
        for (int j = 0; j < 8; ++j) o[j] = (__bf16)wp[j];
    }
}

// ------------------------------------------------ scan -> meta{beg,end,dinv}, cur
__global__ __launch_bounds__(256) void k_off2(const int* __restrict__ cnt, int* __restrict__ gctr,
                                              int4* __restrict__ meta, int* __restrict__ cur) {
    __shared__ int s[256];
    __shared__ int base;
    int t = threadIdx.x, b = blockIdx.x;
    int i = b * 256 + t;
    int v = (i < NN) ? cnt[i] : 0;
    s[t] = v;
    __syncthreads();
    for (int d = 1; d < 256; d <<= 1) {
        int u = (t >= d) ? s[t - d] : 0;
        __syncthreads();
        s[t] += u;
        __syncthreads();
    }
    if (t == 255) base = atomicAdd(gctr, s[255]);
    __syncthreads();
    if (i < NN) {
        int ex = base + s[t] - v;
        cur[i] = ex;
        meta[i] = make_int4(ex, ex + v, __float_as_int(rsqrtf((float)(v + 1))), 0);
    }
}

// ------------------------------------------------ C: gemm (W·x^T, feature-major out) ∥ CSR fill
__global__ __launch_bounds__(256) void k_C(const float* __restrict__ x,
                                           const __bf16* __restrict__ wf,
                                           const int4* __restrict__ meta,
                                           __bf16* __restrict__ g,
                                           const int* __restrict__ src,
                                           const int* __restrict__ dst,
                                           int* __restrict__ cur, int* __restrict__ adj) {
    if (blockIdx.x < GB_GEMM) {
        int gid = blockIdx.x * 4 + (threadIdx.x >> 6);
        if (gid >= NN / 16) return;
        int lane = threadIdx.x & 63;
        int node = gid * 16 + (lane & 15);
        int kg   = lane >> 4;

        f32x4 acc[8];
        #pragma unroll
        for (int ct = 0; ct < 8; ++ct) acc[ct] = (f32x4){0.f, 0.f, 0.f, 0.f};

        #pragma unroll
        for (int kt = 0; kt < 4; ++kt) {
            const float4* xp = (const float4*)(x + (size_t)node * D + kt * 32 + kg * 8);
            float4 x0 = xp[0];
            float4 x1 = xp[1];
            bf16x8 a;
            a[0] = (__bf16)x0.x; a[1] = (__bf16)x0.y; a[2] = (__bf16)x0.z; a[3] = (__bf16)x0.w;
            a[4] = (__bf16)x1.x; a[5] = (__bf16)x1.y; a[6] = (__bf16)x1.z; a[7] = (__bf16)x1.w;
            const bf16x8* wfp = (const bf16x8*)wf + (size_t)kt * 512 + lane;
            #pragma unroll
            for (int ct = 0; ct < 8; ++ct) {
                bf16x8 b = wfp[ct * 64];
                acc[ct] = __builtin_amdgcn_mfma_f32_16x16x32_bf16(b, a, acc[ct], 0, 0, 0);
            }
        }

        float dv = __int_as_float(((const int*)meta)[4 * node + 2]);
        #pragma unroll
        for (int ct = 0; ct < 8; ++ct) {
            bf16x4 o;
            #pragma unroll
            for (int i = 0; i < 4; ++i) o[i] = (__bf16)(acc[ct][i] * dv);
            *(bf16x4*)(g + (size_t)node * D + ct * 16 + kg * 4) = o;
        }
    } else {
        int e = (blockIdx.x - GB_GEMM) * 256 + threadIdx.x;
        if (e >= NE) return;
        int d = dst[e], s = src[e];
        if ((unsigned)d >= (unsigned)NN || (unsigned)s >= (unsigned)NN) return;
        adj[atomicAdd(&cur[d], 1)] = s;
    }
}

// ------------------------------------------------ gather-aggregate, 2 nodes/wave (half-wave split)
// lanes 0-31: node 2w, lanes 32-63: node 2w+1; 4 bf16 features per lane (32*8B = one 256B row).
// Each gather instruction fetches BOTH nodes' neighbor rows. Loop divergence between halves
// is handled by the exec mask; no padding gathers needed.
__global__ __launch_bounds__(256) void k_agg(const float* __restrict__ x,
                                             const __bf16* __restrict__ g,
                                             const int4* __restrict__ meta,
                                             const float* __restrict__ bias,
                                             const int* __restrict__ adj,
                                             float* __restrict__ out) {
    int wave = blockIdx.x * 4 + (threadIdx.x >> 6);
    int lane = threadIdx.x & 63;
    int half = lane >> 5;
    int l5   = lane & 31;
    int node = wave * 2 + half;            // wave < 50000 -> node < NN
    int c0   = l5 * 4;

    int4 m = meta[node];
    int beg = m.x, end = m.y;
    float dv = __int_as_float(m.z);

    float4 xv = *(const float4*)(x + (size_t)node * D + c0);
    float4 bv = *(const float4*)(bias + c0);

    uint2 u = *(const uint2*)(g + (size_t)node * D + c0);   // self loop
    float a0 = bflo(u.x), a1 = bfhi(u.x), a2 = bflo(u.y), a3 = bfhi(u.y);

    for (int i = beg; i < end; i += 4) {
        int s0 = adj[i];
        int s1 = (i + 1 < end) ? adj[i + 1] : NN;
        int s2 = (i + 2 < end) ? adj[i + 2] : NN;
        int s3 = (i + 3 < end) ? adj[i + 3] : NN;
        uint2 v0 = *(const uint2*)(g + (size_t)s0 * D + c0);
        uint2 v1 = *(const uint2*)(g + (size_t)s1 * D + c0);
        uint2 v2 = *(const uint2*)(g + (size_t)s2 * D + c0);
        uint2 v3 = *(const uint2*)(g + (size_t)s3 * D + c0);
        a0 += bflo(v0.x); a1 += bfhi(v0.x); a2 += bflo(v0.y); a3 += bfhi(v0.y);
        a0 += bflo(v1.x); a1 += bfhi(v1.x); a2 += bflo(v1.y); a3 += bfhi(v1.y);
        a0 += bflo(v2.x); a1 += bfhi(v2.x); a2 += bflo(v2.y); a3 += bfhi(v2.y);
        a0 += bflo(v3.x); a1 += bfhi(v3.x); a2 += bflo(v3.y); a3 += bfhi(v3.y);
    }

    f32x4 r;
    r[0] = xv.x + fmaxf(fmaf(dv, a0, bv.x), 0.f);
    r[1] = xv.y + fmaxf(fmaf(dv, a1, bv.y), 0.f);
    r[2] = xv.z + fmaxf(fmaf(dv, a2, bv.z), 0.f);
    r[3] = xv.w + fmaxf(fmaf(dv, a3, bv.w), 0.f);
    __builtin_nontemporal_store(r, (f32x4*)(out + (size_t)node * D + c0));
}

// ------------------------------------------------ launch
extern "C" void kernel_launch(void* const* d_in, const int* in_sizes, int n_in,
                              void* d_out, int out_size, void* d_ws, size_t ws_size,
                              hipStream_t stream) {
    const float* x    = (const float*)d_in[0];
    const int*   ei   = (const int*)d_in[1];      // [2][NE], int32
    const float* W    = (const float*)d_in[2];    // [D][D]
    const float* bias = (const float*)d_in[3];    // [D]
    float* out = (float*)d_out;

    const int* src = ei;
    const int* dst = ei + NE;

    char* p = (char*)d_ws;
    auto take = [&](size_t bytes) {
        char* q = p;
        p += (bytes + 255) & ~(size_t)255;
        return q;
    };
    int*    cnt  = (int*)take((size_t)NN * 4);
    int*    gctr = (int*)take(256);                       // adjacent to cnt -> one memset
    int4*   meta = (int4*)take((size_t)NN * 16);
    int*    cur  = (int*)take((size_t)NN * 4);
    int*    adj  = (int*)take((size_t)(NE + 16) * 4);
    __bf16* wf   = (__bf16*)take((size_t)2048 * 8 * 2);
    __bf16* g    = (__bf16*)take((size_t)(NN + 1) * D * 2);   // +1 zero row

    size_t cntPad = (((size_t)NN * 4 + 255) & ~(size_t)255);
    (void)hipMemsetAsync(cnt, 0, cntPad + 256, stream);   // zeroes cnt + gctr

    k_A   <<<GB_CNT + GB_WP, 256, 0, stream>>>(dst, cnt, W, wf, g);
    k_off2<<<(NN + 255) / 256, 256, 0, stream>>>(cnt, gctr, meta, cur);
    k_C   <<<GB_GEMM + GB_CNT, 256, 0, stream>>>(x, wf, meta, g, src, dst, cur, adj);
    k_agg <<<NN / 8, 256, 0, stream>>>(x, g, meta, bias, adj, out);
}